// Round 4
// baseline (12139.509 us; speedup 1.0000x reference)
//
#include <hip/hip_runtime.h>
#include <math.h>

#define T_  512
#define B_  128
#define H_  256
#define A_  18
#define G4H 1024
#define TB_ (T_*B_)

// d_out layout (floats): [logits T*B*A][baseline T*B][action T*B][hT 2*B*H][cT 2*B*H]
#define OUT_BASE  (TB_*A_)
#define OUT_ACT   (OUT_BASE + TB_)
#define OUT_HT    (OUT_ACT + TB_)
#define OUT_CT    (OUT_HT + 2*B_*H_)

// workspace (floats): double-buffered h per layer (parity = t&1), private c per layer,
// then 8 monotonic barrier cells (128 B apart, memset once per replay)
#define WS_H0  0
#define WS_H1  (2*B_*H_)
#define WS_C0  (4*B_*H_)
#define WS_C1  (5*B_*H_)
#define WS_CTR (6*B_*H_)

#define S_    8                   // timesteps per dispatch
#define NDISP 65                  // ceil(514/8)
#define NCELL 8
#define CSTRIDE 32                // uints -> 128 B between cells

// MULTI-STEP DISPATCH, v4: same lockstep 8-phase structure as v3, but the
// phase barrier has NO cache-maintenance instructions (v3's agent-scope
// release/acquire = buffer_wbl2/inv L2 walks per WG per phase ~= 19 us/phase).
// Instead, ALL cross-WG state (ws h/c buffers) uses relaxed SYSTEM-scope
// atomic loads/stores (global_load/store sc0 sc1): they bypass L1/L2 and are
// served by the die-level memory-side L3, which is shared by all XCDs.
// Visibility: __syncthreads() before arrival drains vmcnt(0) (sc1 stores
// complete at the coherence point); sc-flagged reads can never hit a stale
// L2 line because those lines are never L2-cached. Read-only data (x, done,
// weights, biases) keeps the normal cached path and stays L2-warm across
// phases (no invalidates anymore). Arrival contention: 8 padded cells
// (cell = wg&7, 32 serialized RMWs each instead of 256 on one line),
// monotonic targets 256*(g+1) across the replay -> no per-dispatch reset.
// Co-residency: 135 KB LDS forces 1 WG/CU, grid = 256 = #CUs (proven in v3).

__device__ __forceinline__ float cload(const float* p) {
    return __hip_atomic_load((float*)p, __ATOMIC_RELAXED, __HIP_MEMORY_SCOPE_SYSTEM);
}
__device__ __forceinline__ void cstore(float* p, float v) {
    __hip_atomic_store(p, v, __ATOMIC_RELAXED, __HIP_MEMORY_SCOPE_SYSTEM);
}
__device__ __forceinline__ void load16_cached(float4 dst[4], const float* rowp, int kc) {
    const float4* r4 = (const float4*)rowp;
    #pragma unroll
    for (int q = 0; q < 4; ++q) dst[q] = r4[q*16 + kc];
}
__device__ __forceinline__ void load16_coh(float4 dst[4], const float* rowp, int kc) {
    #pragma unroll
    for (int q = 0; q < 4; ++q) {
        const float* p = rowp + q*64 + kc*4;
        dst[q] = make_float4(cload(p), cload(p+1), cload(p+2), cload(p+3));
    }
}

__global__ __launch_bounds__(512, 1) void lstm_multi(
    const float* __restrict__ x, const int* __restrict__ done,
    const float* __restrict__ h0in, const float* __restrict__ c0in,
    const float* __restrict__ w_ih, const float* __restrict__ w_hh,
    const float* __restrict__ b_ih, const float* __restrict__ b_hh,
    const float* __restrict__ Wp, const float* __restrict__ bp,
    const float* __restrict__ Wb, const float* __restrict__ bb,
    float* __restrict__ out, float* __restrict__ ws, int dsp)
{
    __shared__ __align__(16) float wlds[64*2*H_];      // 128 KB weight slice
    __shared__ __align__(16) float gates[4][16][17];   // 4.25 KB
    __shared__ float hlog[19];

    const int wg   = blockIdx.x;
    const int tid  = threadIdx.x;
    const int l    = wg >> 7;            // 0: layer0, 1: layer1 (+head duty)
    const int wl   = wg & 127;
    const int lane = tid & 63;
    const int w    = tid >> 6;           // wave 0..7
    const int kc   = lane & 15;          // K-chunk owner (16 floats, k = q*64+kc*4)
    const int jq   = lane >> 4;          // batch-quad owner
    const int bt   = wl >> 4, hg = wl & 15, b0 = bt*16;

    // ---- stage weights: 64 gate rows x (wi,wh) -> LDS (coalesced, cached path) ----
    {
        const float* WI = w_ih + (size_t)l*G4H*H_;
        const float* WH = w_hh + (size_t)l*G4H*H_;
        float4* dst = (float4*)wlds;
        #pragma unroll
        for (int k = 0; k < 16; ++k) {                  // 8192 float4 / 512 thr
            const int idx = k*512 + tid;
            const int rs = idx >> 7, rem = idx & 127;
            const int m = rem >> 6, q4 = rem & 63;
            const int r = (rs >> 4)*256 + hg*16 + (rs & 15);
            const float* src = (m ? WH : WI) + (size_t)r*H_;
            dst[idx] = ((const float4*)src)[q4];
        }
    }

    // ---- per-thread persistent state across phases ----
    float bsum[8];
    #pragma unroll
    for (int rr = 0; rr < 8; ++rr) {
        const int rs = w*8 + rr;
        const int r  = (rs >> 4)*256 + hg*16 + (rs & 15);
        bsum[rr] = b_ih[(size_t)l*G4H + r] + b_hh[(size_t)l*G4H + r];
    }
    float4 wpr[3]; float wpb[3];                        // head rows w, w+8, w+16
    if (l == 1) {
        #pragma unroll
        for (int k = 0; k < 3; ++k) {
            const int a = w + 8*k;
            if (a < 19) {
                const float* wr = (a < 18) ? (Wp + (size_t)a*H_) : Wb;
                wpr[k] = ((const float4*)wr)[lane];
                wpb[k] = (a < 18) ? bp[a] : bb[0];
            }
        }
    }
    float cr = 0.f; bool chave = false;                 // c-state in register

    unsigned int* ctr = (unsigned int*)(ws + WS_CTR);
    __syncthreads();                                    // weights staged

    for (int p = 0; p < S_; ++p) {
        const int d = dsp*S_ + p;
        const int t = d - l;
        const bool work   = (t >= 0 && t < T_);
        const bool dohead = (l == 1 && d >= 2 && d - 2 < T_);

        // ---- head for t = d-2 (h1 written 2 phases ago; coherent reads) ----
        if (dohead) {
            const int th = d - 2;
            const float* h1p = ws + WS_H1 + (size_t)(th & 1)*B_*H_ + (size_t)wl*H_ + lane*4;
            float4 h4 = make_float4(cload(h1p), cload(h1p+1), cload(h1p+2), cload(h1p+3));
            #pragma unroll
            for (int k = 0; k < 3; ++k) {
                const int a = w + 8*k;
                if (a < 19) {
                    float s = wpr[k].x*h4.x + wpr[k].y*h4.y + wpr[k].z*h4.z + wpr[k].w*h4.w;
                    s += __shfl_xor(s, 1);  s += __shfl_xor(s, 2);  s += __shfl_xor(s, 4);
                    s += __shfl_xor(s, 8);  s += __shfl_xor(s, 16); s += __shfl_xor(s, 32);
                    if (lane == 0) {
                        float v = s + wpb[k];
                        hlog[a] = v;
                        if (a < 18) out[((size_t)th*B_ + wl)*A_ + a] = v;
                        else        out[OUT_BASE + th*B_ + wl] = v;
                    }
                }
            }
        }

        // ---- gate phase (weights from LDS; activations mixed cached/coherent) ----
        if (work) {
            const float* hrec = (t == 0) ? (h0in + (size_t)l*B_*H_)
                                         : (ws + (l ? WS_H1 : WS_H0) + (size_t)((t-1)&1)*B_*H_);
            const float* xin  = l ? (ws + WS_H0 + (size_t)(t&1)*B_*H_)
                                  : (x + (size_t)t*B_*H_);
            float4 xr[4][4], hr[4][4];
            #pragma unroll
            for (int jj = 0; jj < 4; ++jj) {
                const int b = b0 + jq*4 + jj;
                const float nd = done[t*B_ + b] ? 0.f : 1.f;
                if (l == 0) load16_cached(xr[jj], xin + (size_t)b*H_, kc);   // x: read-only input
                else        load16_coh   (xr[jj], xin + (size_t)b*H_, kc);   // h0(t): cross-WG
                if (t == 0) load16_cached(hr[jj], hrec + (size_t)b*H_, kc);  // h0in: read-only
                else        load16_coh   (hr[jj], hrec + (size_t)b*H_, kc);  // ws: cross-WG
                #pragma unroll
                for (int q = 0; q < 4; ++q) {
                    hr[jj][q].x *= nd; hr[jj][q].y *= nd;
                    hr[jj][q].z *= nd; hr[jj][q].w *= nd;
                }
            }
            const float4* wl4 = (const float4*)wlds;
            #pragma unroll 2
            for (int rr = 0; rr < 8; ++rr) {
                const int rs = w*8 + rr;
                const int g  = rs >> 4, ri = rs & 15;
                const int wb4 = rs*128;
                float4 wiv[4], whv[4];
                #pragma unroll
                for (int q = 0; q < 4; ++q) {
                    wiv[q] = wl4[wb4 + q*16 + kc];
                    whv[q] = wl4[wb4 + 64 + q*16 + kc];
                }
                float acc0 = 0.f, acc1 = 0.f, acc2 = 0.f, acc3 = 0.f;
                #pragma unroll
                for (int q = 0; q < 4; ++q) {
                    acc0 += wiv[q].x*xr[0][q].x + wiv[q].y*xr[0][q].y + wiv[q].z*xr[0][q].z + wiv[q].w*xr[0][q].w
                          + whv[q].x*hr[0][q].x + whv[q].y*hr[0][q].y + whv[q].z*hr[0][q].z + whv[q].w*hr[0][q].w;
                    acc1 += wiv[q].x*xr[1][q].x + wiv[q].y*xr[1][q].y + wiv[q].z*xr[1][q].z + wiv[q].w*xr[1][q].w
                          + whv[q].x*hr[1][q].x + whv[q].y*hr[1][q].y + whv[q].z*hr[1][q].z + whv[q].w*hr[1][q].w;
                    acc2 += wiv[q].x*xr[2][q].x + wiv[q].y*xr[2][q].y + wiv[q].z*xr[2][q].z + wiv[q].w*xr[2][q].w
                          + whv[q].x*hr[2][q].x + whv[q].y*hr[2][q].y + whv[q].z*hr[2][q].z + whv[q].w*hr[2][q].w;
                    acc3 += wiv[q].x*xr[3][q].x + wiv[q].y*xr[3][q].y + wiv[q].z*xr[3][q].z + wiv[q].w*xr[3][q].w
                          + whv[q].x*hr[3][q].x + whv[q].y*hr[3][q].y + whv[q].z*hr[3][q].z + whv[q].w*hr[3][q].w;
                }
                acc0 += __shfl_xor(acc0, 1, 16); acc0 += __shfl_xor(acc0, 2, 16);
                acc0 += __shfl_xor(acc0, 4, 16); acc0 += __shfl_xor(acc0, 8, 16);
                acc1 += __shfl_xor(acc1, 1, 16); acc1 += __shfl_xor(acc1, 2, 16);
                acc1 += __shfl_xor(acc1, 4, 16); acc1 += __shfl_xor(acc1, 8, 16);
                acc2 += __shfl_xor(acc2, 1, 16); acc2 += __shfl_xor(acc2, 2, 16);
                acc2 += __shfl_xor(acc2, 4, 16); acc2 += __shfl_xor(acc2, 8, 16);
                acc3 += __shfl_xor(acc3, 1, 16); acc3 += __shfl_xor(acc3, 2, 16);
                acc3 += __shfl_xor(acc3, 4, 16); acc3 += __shfl_xor(acc3, 8, 16);
                float v = (kc == 0) ? acc0 : (kc == 1) ? acc1 : (kc == 2) ? acc2 : acc3;
                if (kc < 4)
                    gates[g][ri][jq*4 + kc] = v + bsum[rr];
            }
        }

        __syncthreads();          // gates ready (uniform)

        // ---- cell update: c in register, h/c stores write-through (sc0 sc1) ----
        if (work && tid < 256) {
            const int j = tid >> 4, hi = tid & 15;
            const int b = b0 + j, h = hg*16 + hi;
            const float nd = done[t*B_ + b] ? 0.f : 1.f;
            float* cst = ws + (l ? WS_C1 : WS_C0) + (size_t)b*H_ + h;
            if (!chave) {
                cr = (t == 0) ? c0in[(size_t)l*B_*H_ + b*H_ + h] : cload(cst);
                chave = true;
            }
            float cp = cr * nd;
            const float gi = gates[0][hi][j], gf = gates[1][hi][j];
            const float gv = gates[2][hi][j], go = gates[3][hi][j];
            const float ii = 1.f/(1.f + expf(-gi));
            const float ff = 1.f/(1.f + expf(-gf));
            const float gt = tanhf(gv);
            const float oo = 1.f/(1.f + expf(-go));
            const float cl = ff*cp + ii*gt;
            cr = cl;
            cstore(cst, cl);
            float* hout = ws + (l ? WS_H1 : WS_H0) + (size_t)(t&1)*B_*H_;
            cstore(hout + (size_t)b*H_ + h, oo*tanhf(cl));
        }

        // ---- argmax (hlog complete; ordered by the mid __syncthreads) ----
        if (dohead && tid == 0) {
            const int th = d - 2;
            float best = hlog[0]; int bi = 0;
            #pragma unroll
            for (int a = 1; a < A_; ++a) { float v = hlog[a]; if (v > best) { best = v; bi = a; } }
            out[OUT_ACT + th*B_ + wl] = (float)bi;       // strict > = first-max, matches np
        }

        // ---- final state copy (coherent reads of ws) ----
        if (l == 1 && d == 513 && tid < 256) {
            const int idx = wl*H_ + tid;
            out[OUT_HT + idx]         = cload(ws + WS_H0 + B_*H_ + idx);   // h(511) parity 1
            out[OUT_HT + B_*H_ + idx] = cload(ws + WS_H1 + B_*H_ + idx);
            out[OUT_CT + idx]         = cload(ws + WS_C0 + idx);
            out[OUT_CT + B_*H_ + idx] = cload(ws + WS_C1 + idx);
        }

        if (d >= 513) break;       // uniform across the grid

        // ---- fence-free device barrier: monotonic 8-cell arrive-and-wait ----
        if (p < S_ - 1) {
            __syncthreads();       // compiler emits vmcnt(0) before s_barrier:
                                   // all sc1 stores completed at the coherence point
            if (tid == 0) {
                const unsigned tgt = 256u * (unsigned)(dsp*(S_-1) + p + 1);
                __hip_atomic_fetch_add(ctr + (wg & (NCELL-1))*CSTRIDE, 1u,
                                       __ATOMIC_RELAXED, __HIP_MEMORY_SCOPE_SYSTEM);
                for (;;) {
                    unsigned s = 0;
                    #pragma unroll
                    for (int i = 0; i < NCELL; ++i)
                        s += __hip_atomic_load(ctr + i*CSTRIDE,
                                               __ATOMIC_RELAXED, __HIP_MEMORY_SCOPE_SYSTEM);
                    if (s >= tgt) break;
                    __builtin_amdgcn_s_sleep(1);
                }
            }
            __syncthreads();
        }
    }
}

extern "C" void kernel_launch(void* const* d_in, const int* in_sizes, int n_in,
                              void* d_out, int out_size, void* d_ws, size_t ws_size,
                              hipStream_t stream)
{
    const float* x    = (const float*)d_in[0];
    const int*   done = (const int*)  d_in[1];
    const float* h0   = (const float*)d_in[2];
    const float* c0   = (const float*)d_in[3];
    const float* w_ih = (const float*)d_in[4];
    const float* w_hh = (const float*)d_in[5];
    const float* b_ih = (const float*)d_in[6];
    const float* b_hh = (const float*)d_in[7];
    const float* Wp   = (const float*)d_in[8];
    const float* bp   = (const float*)d_in[9];
    const float* Wb   = (const float*)d_in[10];
    const float* bb   = (const float*)d_in[11];
    float* out = (float*)d_out;
    float* ws  = (float*)d_ws;    // 768 KB state + 1 KB barrier cells

    // zero the 8 barrier cells (captured node, re-runs every replay)
    hipMemsetAsync((char*)d_ws + (size_t)WS_CTR*sizeof(float), 0, 1024, stream);

    for (int dsp = 0; dsp < NDISP; ++dsp) {
        lstm_multi<<<dim3(256), dim3(512), 0, stream>>>(
            x, done, h0, c0, w_ih, w_hh, b_ih, b_hh, Wp, bp, Wb, bb, out, ws, dsp);
    }
}

// Round 6
// 7677.950 us; speedup vs baseline: 1.5811x; 1.5811x over previous
//
#include <hip/hip_runtime.h>
#include <math.h>

#define T_  512
#define B_  128
#define H_  256
#define A_  18
#define G4H 1024
#define TB_ (T_*B_)

// d_out layout (floats): [logits T*B*A][baseline T*B][action T*B][hT 2*B*H][cT 2*B*H]
#define OUT_BASE  (TB_*A_)
#define OUT_ACT   (OUT_BASE + TB_)
#define OUT_HT    (OUT_ACT + TB_)
#define OUT_CT    (OUT_HT + 2*B_*H_)

// workspace (floats): double-buffered h per layer (parity = t&1), private c per layer,
// then 256 uint phase-stamp cells (one per WG, memset once per replay)
#define WS_H0  0
#define WS_H1  (2*B_*H_)
#define WS_C0  (4*B_*H_)
#define WS_C1  (5*B_*H_)
#define WS_CTR (6*B_*H_)

// SINGLE-DISPATCH PERSISTENT PIPELINE, v6.
// v5 post-mortem: logits passed but finals/action raced -> the stamp (posted
// sc store) can become visible BEFORE the data stores (different L3 channel
// queues; vmcnt ack for plain posted stores is not coherence-point arrival).
// v4 survived only due to ~20us barrier slack. Fix (no wbl2/inv fences):
// every cross-WG data WRITE is an atomic exchange with USED return value -
// a returning atomic acks only after executing at the L3 bank, so after the
// per-wave vmcnt(0) drain the data is globally visible by construction; the
// stamp (issued after the barrier) can never outrun it. Readers are relaxed
// system-scope (sc) loads, now 64-bit pairs. Explicit s_waitcnt vmcnt(0) in
// every thread before arrival (independent of compiler barrier lowering).
// Cluster barriers (32-WG dependency-closed clusters), store-stamp arrival,
// single dispatch, LDS-resident weights, register-resident c: as v5.

__device__ __forceinline__ float cload(const float* p) {
    return __hip_atomic_load((float*)p, __ATOMIC_RELAXED, __HIP_MEMORY_SCOPE_SYSTEM);
}
__device__ __forceinline__ float4 cload4(const float* p) {   // 16B-aligned
    union { unsigned long long u[2]; float4 f; } r;
    r.u[0] = __hip_atomic_load((const unsigned long long*)p,
                               __ATOMIC_RELAXED, __HIP_MEMORY_SCOPE_SYSTEM);
    r.u[1] = __hip_atomic_load((const unsigned long long*)(p + 2),
                               __ATOMIC_RELAXED, __HIP_MEMORY_SCOPE_SYSTEM);
    return r.f;
}
// ordered data write: atomic exchange, returning form forced by asm sink
__device__ __forceinline__ void cswap(float* p, float v) {
    float old = __hip_atomic_exchange(p, v, __ATOMIC_RELAXED, __HIP_MEMORY_SCOPE_SYSTEM);
    asm volatile("" :: "v"(old));
}
__device__ __forceinline__ void load16_cached(float4 dst[4], const float* rowp, int kc) {
    const float4* r4 = (const float4*)rowp;
    #pragma unroll
    for (int q = 0; q < 4; ++q) dst[q] = r4[q*16 + kc];
}
__device__ __forceinline__ void load16_coh(float4 dst[4], const float* rowp, int kc) {
    #pragma unroll
    for (int q = 0; q < 4; ++q) dst[q] = cload4(rowp + q*64 + kc*4);
}

__global__ __launch_bounds__(512, 1) void lstm_persist(
    const float* __restrict__ x, const int* __restrict__ done,
    const float* __restrict__ h0in, const float* __restrict__ c0in,
    const float* __restrict__ w_ih, const float* __restrict__ w_hh,
    const float* __restrict__ b_ih, const float* __restrict__ b_hh,
    const float* __restrict__ Wp, const float* __restrict__ bp,
    const float* __restrict__ Wb, const float* __restrict__ bb,
    float* __restrict__ out, float* __restrict__ ws)
{
    __shared__ __align__(16) float wlds[64*2*H_];      // 128 KB weight slice
    __shared__ __align__(16) float gates[4][16][17];   // 4.25 KB
    __shared__ float hlog[19];

    const int wg   = blockIdx.x;
    const int tid  = threadIdx.x;
    const int l    = wg >> 7;            // 0: layer0, 1: layer1 (+head duty)
    const int wl   = wg & 127;
    const int lane = tid & 63;
    const int w    = tid >> 6;           // wave 0..7
    const int kc   = lane & 15;          // K-chunk owner (16 floats, k = q*64+kc*4)
    const int jq   = lane >> 4;          // batch-quad owner
    const int bt   = wl >> 4, hg = wl & 15, b0 = bt*16;

    // ---- stage weights ONCE: 64 gate rows x (wi,wh) -> LDS ----
    {
        const float* WI = w_ih + (size_t)l*G4H*H_;
        const float* WH = w_hh + (size_t)l*G4H*H_;
        float4* dst = (float4*)wlds;
        #pragma unroll
        for (int k = 0; k < 16; ++k) {                  // 8192 float4 / 512 thr
            const int idx = k*512 + tid;
            const int rs = idx >> 7, rem = idx & 127;
            const int m = rem >> 6, q4 = rem & 63;
            const int r = (rs >> 4)*256 + hg*16 + (rs & 15);
            const float* src = (m ? WH : WI) + (size_t)r*H_;
            dst[idx] = ((const float4*)src)[q4];
        }
    }

    // ---- per-thread persistent state ----
    float bsum[8];
    #pragma unroll
    for (int rr = 0; rr < 8; ++rr) {
        const int rs = w*8 + rr;
        const int r  = (rs >> 4)*256 + hg*16 + (rs & 15);
        bsum[rr] = b_ih[(size_t)l*G4H + r] + b_hh[(size_t)l*G4H + r];
    }
    float4 wpr[3]; float wpb[3];                        // head rows w, w+8, w+16
    if (l == 1) {
        #pragma unroll
        for (int k = 0; k < 3; ++k) {
            const int a = w + 8*k;
            if (a < 19) {
                const float* wr = (a < 18) ? (Wp + (size_t)a*H_) : Wb;
                wpr[k] = ((const float4*)wr)[lane];
                wpb[k] = (a < 18) ? bp[a] : bb[0];
            }
        }
    }
    float cr = 0.f;                                     // c-state in register all run

    unsigned int* stamp = (unsigned int*)(ws + WS_CTR);
    __syncthreads();                                    // weights staged

    for (int p = 0; p < 514; ++p) {
        const int d = p;
        const int t = d - l;
        const bool work   = (t >= 0 && t < T_);
        const bool dohead = (l == 1 && d >= 2 && d - 2 < T_);

        // ---- head for t = d-2 (h1 written 2 phases ago; coherent reads) ----
        if (dohead) {
            const int th = d - 2;
            const float* h1p = ws + WS_H1 + (size_t)(th & 1)*B_*H_ + (size_t)wl*H_ + lane*4;
            float4 h4 = cload4(h1p);
            #pragma unroll
            for (int k = 0; k < 3; ++k) {
                const int a = w + 8*k;
                if (a < 19) {
                    float s = wpr[k].x*h4.x + wpr[k].y*h4.y + wpr[k].z*h4.z + wpr[k].w*h4.w;
                    s += __shfl_xor(s, 1);  s += __shfl_xor(s, 2);  s += __shfl_xor(s, 4);
                    s += __shfl_xor(s, 8);  s += __shfl_xor(s, 16); s += __shfl_xor(s, 32);
                    if (lane == 0) {
                        float v = s + wpb[k];
                        hlog[a] = v;
                        if (a < 18) out[((size_t)th*B_ + wl)*A_ + a] = v;
                        else        out[OUT_BASE + th*B_ + wl] = v;
                    }
                }
            }
        }

        // ---- gate phase (weights from LDS; activations cached/coherent) ----
        if (work) {
            const float* hrec = (t == 0) ? (h0in + (size_t)l*B_*H_)
                                         : (ws + (l ? WS_H1 : WS_H0) + (size_t)((t-1)&1)*B_*H_);
            const float* xin  = l ? (ws + WS_H0 + (size_t)(t&1)*B_*H_)
                                  : (x + (size_t)t*B_*H_);
            float4 xr[4][4], hr[4][4];
            #pragma unroll
            for (int jj = 0; jj < 4; ++jj) {
                const int b = b0 + jq*4 + jj;
                const float nd = done[t*B_ + b] ? 0.f : 1.f;
                if (l == 0) load16_cached(xr[jj], xin + (size_t)b*H_, kc);   // x: read-only
                else        load16_coh   (xr[jj], xin + (size_t)b*H_, kc);   // h0(t): cross-WG
                if (t == 0) load16_cached(hr[jj], hrec + (size_t)b*H_, kc);  // h0in: read-only
                else        load16_coh   (hr[jj], hrec + (size_t)b*H_, kc);  // ws: cross-WG
                #pragma unroll
                for (int q = 0; q < 4; ++q) {
                    hr[jj][q].x *= nd; hr[jj][q].y *= nd;
                    hr[jj][q].z *= nd; hr[jj][q].w *= nd;
                }
            }
            const float4* wl4 = (const float4*)wlds;
            #pragma unroll 2
            for (int rr = 0; rr < 8; ++rr) {
                const int rs = w*8 + rr;
                const int g  = rs >> 4, ri = rs & 15;
                const int wb4 = rs*128;
                float4 wiv[4], whv[4];
                #pragma unroll
                for (int q = 0; q < 4; ++q) {
                    wiv[q] = wl4[wb4 + q*16 + kc];
                    whv[q] = wl4[wb4 + 64 + q*16 + kc];
                }
                float acc0 = 0.f, acc1 = 0.f, acc2 = 0.f, acc3 = 0.f;
                #pragma unroll
                for (int q = 0; q < 4; ++q) {
                    acc0 += wiv[q].x*xr[0][q].x + wiv[q].y*xr[0][q].y + wiv[q].z*xr[0][q].z + wiv[q].w*xr[0][q].w
                          + whv[q].x*hr[0][q].x + whv[q].y*hr[0][q].y + whv[q].z*hr[0][q].z + whv[q].w*hr[0][q].w;
                    acc1 += wiv[q].x*xr[1][q].x + wiv[q].y*xr[1][q].y + wiv[q].z*xr[1][q].z + wiv[q].w*xr[1][q].w
                          + whv[q].x*hr[1][q].x + whv[q].y*hr[1][q].y + whv[q].z*hr[1][q].z + whv[q].w*hr[1][q].w;
                    acc2 += wiv[q].x*xr[2][q].x + wiv[q].y*xr[2][q].y + wiv[q].z*xr[2][q].z + wiv[q].w*xr[2][q].w
                          + whv[q].x*hr[2][q].x + whv[q].y*hr[2][q].y + whv[q].z*hr[2][q].z + whv[q].w*hr[2][q].w;
                    acc3 += wiv[q].x*xr[3][q].x + wiv[q].y*xr[3][q].y + wiv[q].z*xr[3][q].z + wiv[q].w*xr[3][q].w
                          + whv[q].x*hr[3][q].x + whv[q].y*hr[3][q].y + whv[q].z*hr[3][q].z + whv[q].w*hr[3][q].w;
                }
                acc0 += __shfl_xor(acc0, 1, 16); acc0 += __shfl_xor(acc0, 2, 16);
                acc0 += __shfl_xor(acc0, 4, 16); acc0 += __shfl_xor(acc0, 8, 16);
                acc1 += __shfl_xor(acc1, 1, 16); acc1 += __shfl_xor(acc1, 2, 16);
                acc1 += __shfl_xor(acc1, 4, 16); acc1 += __shfl_xor(acc1, 8, 16);
                acc2 += __shfl_xor(acc2, 1, 16); acc2 += __shfl_xor(acc2, 2, 16);
                acc2 += __shfl_xor(acc2, 4, 16); acc2 += __shfl_xor(acc2, 8, 16);
                acc3 += __shfl_xor(acc3, 1, 16); acc3 += __shfl_xor(acc3, 2, 16);
                acc3 += __shfl_xor(acc3, 4, 16); acc3 += __shfl_xor(acc3, 8, 16);
                float v = (kc == 0) ? acc0 : (kc == 1) ? acc1 : (kc == 2) ? acc2 : acc3;
                if (kc < 4)
                    gates[g][ri][jq*4 + kc] = v + bsum[rr];
            }
        }

        __syncthreads();          // gates ready (uniform)

        // ---- cell update: c in register; cross-WG writes are returning swaps ----
        if (work && tid < 256) {
            const int j = tid >> 4, hi = tid & 15;
            const int b = b0 + j, h = hg*16 + hi;
            const float nd = done[t*B_ + b] ? 0.f : 1.f;
            if (t == 0) cr = c0in[(size_t)l*B_*H_ + b*H_ + h];
            float cp = cr * nd;
            const float gi = gates[0][hi][j], gf = gates[1][hi][j];
            const float gv = gates[2][hi][j], go = gates[3][hi][j];
            const float ii = 1.f/(1.f + expf(-gi));
            const float ff = 1.f/(1.f + expf(-gf));
            const float gt = tanhf(gv);
            const float oo = 1.f/(1.f + expf(-go));
            const float cl = ff*cp + ii*gt;
            cr = cl;
            if (t == T_-1)
                cswap(ws + (l ? WS_C1 : WS_C0) + (size_t)b*H_ + h, cl);
            float* hout = ws + (l ? WS_H1 : WS_H0) + (size_t)(t&1)*B_*H_;
            cswap(hout + (size_t)b*H_ + h, oo*tanhf(cl));
        }

        // ---- argmax (hlog complete; ordered by the mid __syncthreads) ----
        if (dohead && tid == 0) {
            const int th = d - 2;
            float best = hlog[0]; int bi = 0;
            #pragma unroll
            for (int a = 1; a < A_; ++a) { float v = hlog[a]; if (v > best) { best = v; bi = a; } }
            out[OUT_ACT + th*B_ + wl] = (float)bi;       // strict > = first-max, matches np
        }

        // ---- final state copy (cluster-synced by the p=511/512 barriers) ----
        if (l == 1 && d == 513 && tid < 256) {
            const int idx = wl*H_ + tid;
            out[OUT_HT + idx]         = cload(ws + WS_H0 + B_*H_ + idx);   // h0(511) parity 1
            out[OUT_HT + B_*H_ + idx] = cload(ws + WS_H1 + B_*H_ + idx);   // h1(511) parity 1
            out[OUT_CT + idx]         = cload(ws + WS_C0 + idx);
            out[OUT_CT + B_*H_ + idx] = cload(ws + WS_C1 + idx);
        }

        // ---- cluster barrier: swap-acked data, store-stamp arrival, 32-lane poll ----
        if (p < 513) {
            // every wave: all my returning swaps have acked at the L3 bank
            asm volatile("s_waitcnt vmcnt(0)" ::: "memory");
            __syncthreads();
            if (tid == 0)
                __hip_atomic_store(stamp + wg, (unsigned)(p + 1),
                                   __ATOMIC_RELAXED, __HIP_MEMORY_SCOPE_SYSTEM);
            if (tid < 32) {        // lane i polls member i of my 32-WG cluster
                const int cell = (tid < 16) ? (bt*16 + tid) : (128 + bt*16 + (tid - 16));
                while (__hip_atomic_load(stamp + cell, __ATOMIC_RELAXED,
                                         __HIP_MEMORY_SCOPE_SYSTEM) <= (unsigned)p)
                    __builtin_amdgcn_s_sleep(1);
            }
            __syncthreads();
        }
    }
}

extern "C" void kernel_launch(void* const* d_in, const int* in_sizes, int n_in,
                              void* d_out, int out_size, void* d_ws, size_t ws_size,
                              hipStream_t stream)
{
    const float* x    = (const float*)d_in[0];
    const int*   done = (const int*)  d_in[1];
    const float* h0   = (const float*)d_in[2];
    const float* c0   = (const float*)d_in[3];
    const float* w_ih = (const float*)d_in[4];
    const float* w_hh = (const float*)d_in[5];
    const float* b_ih = (const float*)d_in[6];
    const float* b_hh = (const float*)d_in[7];
    const float* Wp   = (const float*)d_in[8];
    const float* bp   = (const float*)d_in[9];
    const float* Wb   = (const float*)d_in[10];
    const float* bb   = (const float*)d_in[11];
    float* out = (float*)d_out;
    float* ws  = (float*)d_ws;    // 768 KB state + 1 KB stamp cells

    // zero the 256 stamp cells (captured node, re-runs every replay)
    hipMemsetAsync((char*)d_ws + (size_t)WS_CTR*sizeof(float), 0, 1024, stream);

    lstm_persist<<<dim3(256), dim3(512), 0, stream>>>(
        x, done, h0, c0, w_ih, w_hh, b_ih, b_hh, Wp, bp, Wb, bb, out, ws);
}

// Round 7
// 6542.462 us; speedup vs baseline: 1.8555x; 1.1736x over previous
//
#include <hip/hip_runtime.h>
#include <math.h>

#define T_  512
#define B_  128
#define H_  256
#define A_  18
#define G4H 1024
#define TB_ (T_*B_)

// d_out layout (floats): [logits T*B*A][baseline T*B][action T*B][hT 2*B*H][cT 2*B*H]
#define OUT_BASE  (TB_*A_)
#define OUT_ACT   (OUT_BASE + TB_)
#define OUT_HT    (OUT_ACT + TB_)
#define OUT_CT    (OUT_HT + 2*B_*H_)

// workspace (floats): double-buffered h per layer (parity = t&1), private c per layer,
// then 256 uint phase-stamp cells (one per WG, memset once per replay)
#define WS_H0  0
#define WS_H1  (2*B_*H_)
#define WS_C0  (4*B_*H_)
#define WS_C1  (5*B_*H_)
#define WS_CTR (6*B_*H_)

// SINGLE-DISPATCH PERSISTENT PIPELINE, v7.
// v6 post-mortem: passed at 15.8 us/phase but ~10 us is uncached-load overhead:
// all 8 waves of a WG loaded the IDENTICAL 16 KB activation set via 8B-granule
// system-scope loads (256 wave-transactions per L1 WG, ~49 MB/phase of fabric
// traffic for 6 MB unique; FETCH_SIZE showed 1.6 MB/phase HBM). Fix: stage each
// sc stream into LDS once per phase - a contiguous 16 KB block copy (512 thr x
// 32 B, coalesced, ONE round trip), then all waves read from LDS (conflict-free
// pattern). done-mask applied at staging. Sync skeleton is v6's proven one:
// cross-WG data writes = returning atomic swaps (acked at coherence point by
// vmcnt(0)), store-stamp arrival, 32-lane poll of the 32-WG dependency-closed
// cluster, no cache-maintenance fences anywhere.

__device__ __forceinline__ float cload(const float* p) {
    return __hip_atomic_load((float*)p, __ATOMIC_RELAXED, __HIP_MEMORY_SCOPE_SYSTEM);
}
__device__ __forceinline__ float4 cload4(const float* p) {   // 16B-aligned
    union { unsigned long long u[2]; float4 f; } r;
    r.u[0] = __hip_atomic_load((const unsigned long long*)p,
                               __ATOMIC_RELAXED, __HIP_MEMORY_SCOPE_SYSTEM);
    r.u[1] = __hip_atomic_load((const unsigned long long*)(p + 2),
                               __ATOMIC_RELAXED, __HIP_MEMORY_SCOPE_SYSTEM);
    return r.f;
}
// ordered data write: atomic exchange, returning form forced by asm sink
__device__ __forceinline__ void cswap(float* p, float v) {
    float old = __hip_atomic_exchange(p, v, __ATOMIC_RELAXED, __HIP_MEMORY_SCOPE_SYSTEM);
    asm volatile("" :: "v"(old));
}

__global__ __launch_bounds__(512, 1) void lstm_persist(
    const float* __restrict__ x, const int* __restrict__ done,
    const float* __restrict__ h0in, const float* __restrict__ c0in,
    const float* __restrict__ w_ih, const float* __restrict__ w_hh,
    const float* __restrict__ b_ih, const float* __restrict__ b_hh,
    const float* __restrict__ Wp, const float* __restrict__ bp,
    const float* __restrict__ Wb, const float* __restrict__ bb,
    float* __restrict__ out, float* __restrict__ ws)
{
    __shared__ __align__(16) float wlds[64*2*H_];      // 128 KB weight slice
    __shared__ __align__(16) float stg[16*H_];         // 16 KB activation stage
    __shared__ __align__(16) float gates[4][16][17];   // 4.25 KB
    __shared__ float hlog[19];
    // total ~151.9 KB < 160 KB; 1 WG/CU (required for co-residency)

    const int wg   = blockIdx.x;
    const int tid  = threadIdx.x;
    const int l    = wg >> 7;            // 0: layer0, 1: layer1 (+head duty)
    const int wl   = wg & 127;
    const int lane = tid & 63;
    const int w    = tid >> 6;           // wave 0..7
    const int kc   = lane & 15;          // K-chunk owner (16 floats, k = q*64+kc*4)
    const int jq   = lane >> 4;          // batch-quad owner
    const int bt   = wl >> 4, hg = wl & 15, b0 = bt*16;

    // ---- stage weights ONCE: 64 gate rows x (wi,wh) -> LDS ----
    {
        const float* WI = w_ih + (size_t)l*G4H*H_;
        const float* WH = w_hh + (size_t)l*G4H*H_;
        float4* dst = (float4*)wlds;
        #pragma unroll
        for (int k = 0; k < 16; ++k) {                  // 8192 float4 / 512 thr
            const int idx = k*512 + tid;
            const int rs = idx >> 7, rem = idx & 127;
            const int m = rem >> 6, q4 = rem & 63;
            const int r = (rs >> 4)*256 + hg*16 + (rs & 15);
            const float* src = (m ? WH : WI) + (size_t)r*H_;
            dst[idx] = ((const float4*)src)[q4];
        }
    }

    // ---- per-thread persistent state ----
    float bsum[8];
    #pragma unroll
    for (int rr = 0; rr < 8; ++rr) {
        const int rs = w*8 + rr;
        const int r  = (rs >> 4)*256 + hg*16 + (rs & 15);
        bsum[rr] = b_ih[(size_t)l*G4H + r] + b_hh[(size_t)l*G4H + r];
    }
    float4 wpr[3]; float wpb[3];                        // head rows w, w+8, w+16
    if (l == 1) {
        #pragma unroll
        for (int k = 0; k < 3; ++k) {
            const int a = w + 8*k;
            if (a < 19) {
                const float* wr = (a < 18) ? (Wp + (size_t)a*H_) : Wb;
                wpr[k] = ((const float4*)wr)[lane];
                wpb[k] = (a < 18) ? bp[a] : bb[0];
            }
        }
    }
    float cr = 0.f;                                     // c-state in register all run

    // staging geometry: thread covers 8 consecutive floats at offset tid*8
    const int sb = b0 + (tid >> 5);                     // batch of my staged chunk

    unsigned int* stamp = (unsigned int*)(ws + WS_CTR);
    __syncthreads();                                    // weights staged

    for (int p = 0; p < 514; ++p) {
        const int d = p;
        const int t = d - l;
        const bool work   = (t >= 0 && t < T_);
        const bool dohead = (l == 1 && d >= 2 && d - 2 < T_);

        // ---- head for t = d-2 (h1 written 2 phases ago; coherent reads) ----
        if (dohead) {
            const int th = d - 2;
            const float* h1p = ws + WS_H1 + (size_t)(th & 1)*B_*H_ + (size_t)wl*H_ + lane*4;
            float4 h4 = cload4(h1p);
            #pragma unroll
            for (int k = 0; k < 3; ++k) {
                const int a = w + 8*k;
                if (a < 19) {
                    float s = wpr[k].x*h4.x + wpr[k].y*h4.y + wpr[k].z*h4.z + wpr[k].w*h4.w;
                    s += __shfl_xor(s, 1);  s += __shfl_xor(s, 2);  s += __shfl_xor(s, 4);
                    s += __shfl_xor(s, 8);  s += __shfl_xor(s, 16); s += __shfl_xor(s, 32);
                    if (lane == 0) {
                        float v = s + wpb[k];
                        hlog[a] = v;
                        if (a < 18) out[((size_t)th*B_ + wl)*A_ + a] = v;
                        else        out[OUT_BASE + th*B_ + wl] = v;
                    }
                }
            }
        }

        // ---- gate phase ----
        if (work) {
            float4 xr[4][4], hr[4][4];
            const float4* s4 = (const float4*)stg;

            // -- xr: L0 reads global x (cached); L1 stages h0(t) through LDS --
            if (l == 0) {
                const float4* xb0 = (const float4*)(x + ((size_t)t*B_ + b0)*H_);
                #pragma unroll
                for (int jj = 0; jj < 4; ++jj)
                    #pragma unroll
                    for (int q = 0; q < 4; ++q)
                        xr[jj][q] = xb0[(size_t)(jq*4 + jj)*64 + q*16 + kc];
            } else {
                const float* src = ws + WS_H0 + (size_t)(t&1)*B_*H_ + (size_t)b0*H_ + tid*8;
                float4 a = cload4(src), b2 = cload4(src + 4);     // one coalesced round
                ((float4*)stg)[tid*2]     = a;
                ((float4*)stg)[tid*2 + 1] = b2;
                __syncthreads();
                #pragma unroll
                for (int jj = 0; jj < 4; ++jj)
                    #pragma unroll
                    for (int q = 0; q < 4; ++q)
                        xr[jj][q] = s4[(jq*4 + jj)*64 + q*16 + kc];
                __syncthreads();                                  // before reuse for h
            }

            // -- hr: stage recurrent h (masked at staging) --
            {
                const float nd = done[t*B_ + sb] ? 0.f : 1.f;
                float4 a, b2;
                if (t == 0) {                                     // h0in: read-only, cached
                    const float* src = h0in + (size_t)l*B_*H_ + (size_t)b0*H_ + tid*8;
                    a = ((const float4*)src)[0]; b2 = ((const float4*)src)[1];
                } else {                                          // ws: cross-WG, coherent
                    const float* src = ws + (l ? WS_H1 : WS_H0) + (size_t)((t-1)&1)*B_*H_
                                     + (size_t)b0*H_ + tid*8;
                    a = cload4(src); b2 = cload4(src + 4);
                }
                a.x *= nd;  a.y *= nd;  a.z *= nd;  a.w *= nd;
                b2.x *= nd; b2.y *= nd; b2.z *= nd; b2.w *= nd;
                ((float4*)stg)[tid*2]     = a;
                ((float4*)stg)[tid*2 + 1] = b2;
                __syncthreads();
                #pragma unroll
                for (int jj = 0; jj < 4; ++jj)
                    #pragma unroll
                    for (int q = 0; q < 4; ++q)
                        hr[jj][q] = s4[(jq*4 + jj)*64 + q*16 + kc];
            }

            // -- FMA: 8 gate rows per wave, weights from LDS --
            const float4* wl4 = (const float4*)wlds;
            #pragma unroll 2
            for (int rr = 0; rr < 8; ++rr) {
                const int rs = w*8 + rr;
                const int g  = rs >> 4, ri = rs & 15;
                const int wb4 = rs*128;
                float4 wiv[4], whv[4];
                #pragma unroll
                for (int q = 0; q < 4; ++q) {
                    wiv[q] = wl4[wb4 + q*16 + kc];
                    whv[q] = wl4[wb4 + 64 + q*16 + kc];
                }
                float acc0 = 0.f, acc1 = 0.f, acc2 = 0.f, acc3 = 0.f;
                #pragma unroll
                for (int q = 0; q < 4; ++q) {
                    acc0 += wiv[q].x*xr[0][q].x + wiv[q].y*xr[0][q].y + wiv[q].z*xr[0][q].z + wiv[q].w*xr[0][q].w
                          + whv[q].x*hr[0][q].x + whv[q].y*hr[0][q].y + whv[q].z*hr[0][q].z + whv[q].w*hr[0][q].w;
                    acc1 += wiv[q].x*xr[1][q].x + wiv[q].y*xr[1][q].y + wiv[q].z*xr[1][q].z + wiv[q].w*xr[1][q].w
                          + whv[q].x*hr[1][q].x + whv[q].y*hr[1][q].y + whv[q].z*hr[1][q].z + whv[q].w*hr[1][q].w;
                    acc2 += wiv[q].x*xr[2][q].x + wiv[q].y*xr[2][q].y + wiv[q].z*xr[2][q].z + wiv[q].w*xr[2][q].w
                          + whv[q].x*hr[2][q].x + whv[q].y*hr[2][q].y + whv[q].z*hr[2][q].z + whv[q].w*hr[2][q].w;
                    acc3 += wiv[q].x*xr[3][q].x + wiv[q].y*xr[3][q].y + wiv[q].z*xr[3][q].z + wiv[q].w*xr[3][q].w
                          + whv[q].x*hr[3][q].x + whv[q].y*hr[3][q].y + whv[q].z*hr[3][q].z + whv[q].w*hr[3][q].w;
                }
                acc0 += __shfl_xor(acc0, 1, 16); acc0 += __shfl_xor(acc0, 2, 16);
                acc0 += __shfl_xor(acc0, 4, 16); acc0 += __shfl_xor(acc0, 8, 16);
                acc1 += __shfl_xor(acc1, 1, 16); acc1 += __shfl_xor(acc1, 2, 16);
                acc1 += __shfl_xor(acc1, 4, 16); acc1 += __shfl_xor(acc1, 8, 16);
                acc2 += __shfl_xor(acc2, 1, 16); acc2 += __shfl_xor(acc2, 2, 16);
                acc2 += __shfl_xor(acc2, 4, 16); acc2 += __shfl_xor(acc2, 8, 16);
                acc3 += __shfl_xor(acc3, 1, 16); acc3 += __shfl_xor(acc3, 2, 16);
                acc3 += __shfl_xor(acc3, 4, 16); acc3 += __shfl_xor(acc3, 8, 16);
                float v = (kc == 0) ? acc0 : (kc == 1) ? acc1 : (kc == 2) ? acc2 : acc3;
                if (kc < 4)
                    gates[g][ri][jq*4 + kc] = v + bsum[rr];
            }
        }

        __syncthreads();          // gates ready (uniform)

        // ---- cell update: c in register; cross-WG writes are returning swaps ----
        if (work && tid < 256) {
            const int j = tid >> 4, hi = tid & 15;
            const int b = b0 + j, h = hg*16 + hi;
            const float nd = done[t*B_ + b] ? 0.f : 1.f;
            if (t == 0) cr = c0in[(size_t)l*B_*H_ + b*H_ + h];
            float cp = cr * nd;
            const float gi = gates[0][hi][j], gf = gates[1][hi][j];
            const float gv = gates[2][hi][j], go = gates[3][hi][j];
            const float ii = 1.f/(1.f + expf(-gi));
            const float ff = 1.f/(1.f + expf(-gf));
            const float gt = tanhf(gv);
            const float oo = 1.f/(1.f + expf(-go));
            const float cl = ff*cp + ii*gt;
            cr = cl;
            if (t == T_-1)
                cswap(ws + (l ? WS_C1 : WS_C0) + (size_t)b*H_ + h, cl);
            float* hout = ws + (l ? WS_H1 : WS_H0) + (size_t)(t&1)*B_*H_;
            cswap(hout + (size_t)b*H_ + h, oo*tanhf(cl));
        }

        // ---- argmax (hlog complete; ordered by the mid __syncthreads) ----
        if (dohead && tid == 0) {
            const int th = d - 2;
            float best = hlog[0]; int bi = 0;
            #pragma unroll
            for (int a = 1; a < A_; ++a) { float v = hlog[a]; if (v > best) { best = v; bi = a; } }
            out[OUT_ACT + th*B_ + wl] = (float)bi;       // strict > = first-max, matches np
        }

        // ---- final state copy (cluster-synced by the p=511/512 barriers) ----
        if (l == 1 && d == 513 && tid < 256) {
            const int idx = wl*H_ + tid;
            out[OUT_HT + idx]         = cload(ws + WS_H0 + B_*H_ + idx);   // h0(511) parity 1
            out[OUT_HT + B_*H_ + idx] = cload(ws + WS_H1 + B_*H_ + idx);   // h1(511) parity 1
            out[OUT_CT + idx]         = cload(ws + WS_C0 + idx);
            out[OUT_CT + B_*H_ + idx] = cload(ws + WS_C1 + idx);
        }

        // ---- cluster barrier: swap-acked data, store-stamp arrival, 32-lane poll ----
        if (p < 513) {
            // every wave: all my returning swaps have acked at the L3 bank
            asm volatile("s_waitcnt vmcnt(0)" ::: "memory");
            __syncthreads();
            if (tid == 0)
                __hip_atomic_store(stamp + wg, (unsigned)(p + 1),
                                   __ATOMIC_RELAXED, __HIP_MEMORY_SCOPE_SYSTEM);
            if (tid < 32) {        // lane i polls member i of my 32-WG cluster
                const int cell = (tid < 16) ? (bt*16 + tid) : (128 + bt*16 + (tid - 16));
                while (__hip_atomic_load(stamp + cell, __ATOMIC_RELAXED,
                                         __HIP_MEMORY_SCOPE_SYSTEM) <= (unsigned)p)
                    __builtin_amdgcn_s_sleep(1);
            }
            __syncthreads();
        }
    }
}

extern "C" void kernel_launch(void* const* d_in, const int* in_sizes, int n_in,
                              void* d_out, int out_size, void* d_ws, size_t ws_size,
                              hipStream_t stream)
{
    const float* x    = (const float*)d_in[0];
    const int*   done = (const int*)  d_in[1];
    const float* h0   = (const float*)d_in[2];
    const float* c0   = (const float*)d_in[3];
    const float* w_ih = (const float*)d_in[4];
    const float* w_hh = (const float*)d_in[5];
    const float* b_ih = (const float*)d_in[6];
    const float* b_hh = (const float*)d_in[7];
    const float* Wp   = (const float*)d_in[8];
    const float* bp   = (const float*)d_in[9];
    const float* Wb   = (const float*)d_in[10];
    const float* bb   = (const float*)d_in[11];
    float* out = (float*)d_out;
    float* ws  = (float*)d_ws;    // 768 KB state + 1 KB stamp cells

    // zero the 256 stamp cells (captured node, re-runs every replay)
    hipMemsetAsync((char*)d_ws + (size_t)WS_CTR*sizeof(float), 0, 1024, stream);

    lstm_persist<<<dim3(256), dim3(512), 0, stream>>>(
        x, done, h0, c0, w_ih, w_hh, b_ih, b_hh, Wp, bp, Wb, bb, out, ws);
}